// Round 11
// baseline (345.426 us; speedup 1.0000x reference)
//
#include <hip/hip_runtime.h>
#include <hip/hip_fp16.h>

// GCN 2-layer forward: CSR-gather + fp16-MFMA GEMMs (fp32 accumulate).
// N=50000, E=800000, IN=128, HID=128, OUT=64.
// R11: R7 structure + XCD-sharded gather128 (col_group = blockIdx%8 -> each XCD's
//      L2 sees only a 1.6MB h1 column slice). gather64 kept in R7-proven form.
//      W1/W2 converted fp32->fp16 inline during GEMM LDS staging.

typedef _Float16 f16;
typedef __attribute__((ext_vector_type(8))) _Float16 f16x8;
typedef __attribute__((ext_vector_type(4))) float f32x4;

// Histogram + per-edge within-row position.
__global__ __launch_bounds__(256) void deg_pos_kernel(const int* __restrict__ dst,
                                                      int* __restrict__ deg,
                                                      int* __restrict__ posw, int E) {
    int e = blockIdx.x * 256 + threadIdx.x;
    if (e < E) posw[e] = atomicAdd(&deg[dst[e]], 1);
}

// Per-block exclusive scan (block=1024); block sums to bsum; dinv on the side.
__global__ __launch_bounds__(1024) void scan1_kernel(const int* __restrict__ deg,
                                                     int* __restrict__ rowptr,
                                                     int* __restrict__ bsum,
                                                     float* __restrict__ dinv, int N) {
    __shared__ int wsum[16];
    const int tid = threadIdx.x, lane = tid & 63, wid = tid >> 6;
    const int idx = blockIdx.x * 1024 + tid;
    int v = (idx < N) ? deg[idx] : 0;
    if (idx < N) dinv[idx] = rsqrtf((float)v + 1.0f);
    int incl = v;
#pragma unroll
    for (int off = 1; off < 64; off <<= 1) {
        int t = __shfl_up(incl, off, 64);
        if (lane >= off) incl += t;
    }
    if (lane == 63) wsum[wid] = incl;
    __syncthreads();
    if (wid == 0) {
        int s = (lane < 16) ? wsum[lane] : 0;
#pragma unroll
        for (int off = 1; off < 16; off <<= 1) {
            int t = __shfl_up(s, off, 64);
            if (lane >= off) s += t;
        }
        if (lane < 16) wsum[lane] = s;
    }
    __syncthreads();
    int waveoff = (wid == 0) ? 0 : wsum[wid - 1];
    if (idx < N) rowptr[idx] = waveoff + incl - v;
    if (tid == 1023) bsum[blockIdx.x] = waveoff + incl;
}

// Merged scan2+scan3: each block adds its exclusive prefix of bsum (nb<=64);
// block 0 also writes rowptr[N] = total.
__global__ __launch_bounds__(1024) void scan23_kernel(int* __restrict__ rowptr,
                                                      const int* __restrict__ bsum,
                                                      int N, int nb) {
    __shared__ int pfx_s;
    const int tid = threadIdx.x;
    if (tid < 64) {
        int v = (tid < nb && tid < blockIdx.x) ? bsum[tid] : 0;
#pragma unroll
        for (int off = 32; off; off >>= 1) v += __shfl_xor(v, off, 64);
        if (tid == 0) pfx_s = v;
    }
    if (blockIdx.x == 0 && tid >= 64 && tid < 128) {
        int l = tid - 64;
        int v = (l < nb) ? bsum[l] : 0;
#pragma unroll
        for (int off = 32; off; off >>= 1) v += __shfl_xor(v, off, 64);
        if (l == 0) rowptr[N] = v;
    }
    __syncthreads();
    int idx = blockIdx.x * 1024 + tid;
    if (idx < N) rowptr[idx] += pfx_s;
}

// GEMM body: H[N][KOUT](fp16) = X[N][128] @ W(fp32 row-major [128][KOUT]).
// W converted fp16 + transposed into LDS (Wl[c*136+k]) during staging.
template <int KOUT, bool F32IN>
__device__ __forceinline__ void gemm_body(int bid, const void* __restrict__ Xv,
                                          const float* __restrict__ W,
                                          f16* __restrict__ H, int N, f16* Wl) {
    constexpr int CT = KOUT / 16;
    const int tid = threadIdx.x;
    for (int i4 = tid; i4 < 128 * KOUT / 4; i4 += 256) {
        int flat = i4 * 4;
        int k = flat / KOUT, c = flat % KOUT;
        float4 w = *(const float4*)&W[flat];
        Wl[(c + 0) * 136 + k] = (f16)w.x;
        Wl[(c + 1) * 136 + k] = (f16)w.y;
        Wl[(c + 2) * 136 + k] = (f16)w.z;
        Wl[(c + 3) * 136 + k] = (f16)w.w;
    }
    __syncthreads();

    const int lane = tid & 63, wid = tid >> 6;
    const int c = lane & 15, kseg = lane >> 4;
    const int row0 = bid * 64 + wid * 16;
    int arow = row0 + c;
    if (arow >= N) arow = N - 1;

    f32x4 acc[CT];
#pragma unroll
    for (int t = 0; t < CT; ++t) acc[t] = (f32x4){0.f, 0.f, 0.f, 0.f};

#pragma unroll
    for (int kt = 0; kt < 4; ++kt) {
        const int k0 = kt * 32;
        f16x8 a;
        if (F32IN) {
            const float* xp = (const float*)Xv + (long)arow * 128 + k0 + kseg * 8;
            float4 x0 = *(const float4*)xp;
            float4 x1 = *(const float4*)(xp + 4);
            a[0] = (f16)x0.x; a[1] = (f16)x0.y; a[2] = (f16)x0.z; a[3] = (f16)x0.w;
            a[4] = (f16)x1.x; a[5] = (f16)x1.y; a[6] = (f16)x1.z; a[7] = (f16)x1.w;
        } else {
            a = *(const f16x8*)((const f16*)Xv + (long)arow * 128 + k0 + kseg * 8);
        }
#pragma unroll
        for (int ct = 0; ct < CT; ++ct) {
            f16x8 b = *(const f16x8*)&Wl[(ct * 16 + c) * 136 + k0 + kseg * 8];
            acc[ct] = __builtin_amdgcn_mfma_f32_16x16x32_f16(a, b, acc[ct], 0, 0, 0);
        }
    }

    const int rbase = row0 + kseg * 4;
#pragma unroll
    for (int ct = 0; ct < CT; ++ct)
#pragma unroll
        for (int r = 0; r < 4; ++r) {
            int row = rbase + r;
            if (row < N) H[(long)row * KOUT + ct * 16 + c] = (f16)acc[ct][r];
        }
}

// Standalone gemm (layer 2).
template <int KOUT, bool F32IN>
__global__ __launch_bounds__(256) void gemm_kernel(const void* __restrict__ Xv,
                                                   const float* __restrict__ W,
                                                   f16* __restrict__ H, int N) {
    __shared__ f16 Wl[KOUT * 136];
    gemm_body<KOUT, F32IN>(blockIdx.x, Xv, W, H, N, Wl);
}

// Fused: blocks [0,GB) run gemm128 x@W1->h1; blocks [GB,GB+FB) do CSR fill.
__global__ __launch_bounds__(256) void fill_gemm_kernel(const int* __restrict__ src,
                                                        const int* __restrict__ dst,
                                                        const int* __restrict__ posw,
                                                        const float* __restrict__ dinv,
                                                        const int* __restrict__ rowptr,
                                                        float2* __restrict__ pairs, int E,
                                                        const float* __restrict__ x,
                                                        const float* __restrict__ W1,
                                                        f16* __restrict__ h1, int N, int GB) {
    __shared__ f16 Wl[128 * 136];
    if ((int)blockIdx.x < GB) {
        gemm_body<128, true>(blockIdx.x, x, W1, h1, N, Wl);
        return;
    }
    int e = (blockIdx.x - GB) * 256 + threadIdx.x;
    if (e >= E) return;
    int s = src[e], d = dst[e];
    float2 p;
    p.x = __int_as_float(s);
    p.y = dinv[s] * dinv[d];
    pairs[rowptr[d] + posw[e]] = p;
}

// XCD-sharded layer-1 gather: col_group = blockIdx%8 (rides HW round-robin
// blockIdx->XCD), each group covers 16 cols (8 half2, 32B slice of each row).
// Wave = 1 node at a time (8 nodes per wave, 4 waves/block); lanes split
// 8 edges x 8 half2-cols; butterfly-reduce over the edge axis.
__global__ __launch_bounds__(256) void gather128_shard_kernel(const __half2* __restrict__ Hu,
                                                              const int* __restrict__ rowptr,
                                                              const float2* __restrict__ pairs,
                                                              const float* __restrict__ dinv,
                                                              const float* __restrict__ b1,
                                                              __half2* __restrict__ z1, int N) {
    const int g = blockIdx.x & 7;        // col group -> fixed XCD
    const int tile = blockIdx.x >> 3;
    const int tid = threadIdx.x;
    const int wid = tid >> 6, lane = tid & 63;
    const int es = lane >> 3;            // edge slot 0..7
    const int c = lane & 7;              // half2 col within slice
    const int col = g * 8 + c;           // half2 col 0..63
    const float2 bz = ((const float2*)b1)[col];

    const int node0 = tile * 32 + wid * 8;
#pragma unroll 1
    for (int nn = 0; nn < 8; ++nn) {
        const int node = node0 + nn;
        if (node >= N) return;
        const int start = rowptr[node], end = rowptr[node + 1];

        float ax = 0.f, ay = 0.f;
        int e = start;
        for (; e + 7 < end; e += 8) {
            float2 p = pairs[e + es];
            float2 f = __half22float2(Hu[(long)__float_as_int(p.x) * 64 + col]);
            ax += f.x * p.y;
            ay += f.y * p.y;
        }
        if (e + es < end) {
            float2 p = pairs[e + es];
            float2 f = __half22float2(Hu[(long)__float_as_int(p.x) * 64 + col]);
            ax += f.x * p.y;
            ay += f.y * p.y;
        }
        // reduce across edge slots (lane bits 3..5)
        ax += __shfl_xor(ax, 8);  ay += __shfl_xor(ay, 8);
        ax += __shfl_xor(ax, 16); ay += __shfl_xor(ay, 16);
        ax += __shfl_xor(ax, 32); ay += __shfl_xor(ay, 32);

        if (es == 0) {
            float di = dinv[node];
            float d2 = di * di;
            float2 fs = __half22float2(Hu[(long)node * 64 + col]);
            float zx = fmaxf(ax + fs.x * d2 + bz.x, 0.f);
            float zy = fmaxf(ay + fs.y * d2 + bz.y, 0.f);
            z1[(long)node * 64 + col] = __float22half2_rn(make_float2(zx, zy));
        }
    }
}

// Layer-2 gather: one wave per node, 1 half/lane, float4-pair bursts (R7-proven).
__global__ __launch_bounds__(256) void gather64_kernel(const __half* __restrict__ H,
                                                       const int* __restrict__ rowptr,
                                                       const float2* __restrict__ pairs,
                                                       const float* __restrict__ dinv,
                                                       const float* __restrict__ bias,
                                                       float* __restrict__ out, int N) {
    const int wid = threadIdx.x >> 6;
    const int lane = threadIdx.x & 63;
    const int node = blockIdx.x * 4 + wid;
    if (node >= N) return;
    const int start = rowptr[node], end = rowptr[node + 1];
    const float4* pp4 = (const float4*)pairs;

    float acc = 0.f;
    int e = start;
    if ((e & 1) && e < end) {
        float2 p0 = pairs[e];
        acc += __half2float(H[(long)__float_as_int(p0.x) * 64 + lane]) * p0.y;
        ++e;
    }
    for (; e + 15 < end; e += 16) {
        float4 q[8];
#pragma unroll
        for (int j = 0; j < 8; ++j) q[j] = pp4[(e >> 1) + j];
        __half uu[16];
#pragma unroll
        for (int j = 0; j < 8; ++j) {
            uu[2 * j]     = H[(long)__float_as_int(q[j].x) * 64 + lane];
            uu[2 * j + 1] = H[(long)__float_as_int(q[j].z) * 64 + lane];
        }
#pragma unroll
        for (int j = 0; j < 8; ++j)
            acc += __half2float(uu[2 * j]) * q[j].y + __half2float(uu[2 * j + 1]) * q[j].w;
    }
    for (; e + 3 < end; e += 4) {
        float4 q0 = pp4[e >> 1], q1 = pp4[(e >> 1) + 1];
        float h0 = __half2float(H[(long)__float_as_int(q0.x) * 64 + lane]);
        float h1 = __half2float(H[(long)__float_as_int(q0.z) * 64 + lane]);
        float h2 = __half2float(H[(long)__float_as_int(q1.x) * 64 + lane]);
        float h3 = __half2float(H[(long)__float_as_int(q1.z) * 64 + lane]);
        acc += h0 * q0.y + h1 * q0.w + h2 * q1.y + h3 * q1.w;
    }
    for (; e < end; ++e) {
        float2 p0 = pairs[e];
        acc += __half2float(H[(long)__float_as_int(p0.x) * 64 + lane]) * p0.y;
    }
    float di = dinv[node];
    float z = acc + __half2float(H[(long)node * 64 + lane]) * (di * di) + bias[lane];
    out[(long)node * 64 + lane] = z;
}

extern "C" void kernel_launch(void* const* d_in, const int* in_sizes, int n_in,
                              void* d_out, int out_size, void* d_ws, size_t ws_size,
                              hipStream_t stream) {
    const float* x  = (const float*)d_in[0];
    const int*   ei = (const int*)d_in[1];
    const float* W1 = (const float*)d_in[2];
    const float* b1 = (const float*)d_in[3];
    const float* W2 = (const float*)d_in[4];
    const float* b2 = (const float*)d_in[5];
    float* out = (float*)d_out;

    const int N = in_sizes[0] / 128;  // 50000
    const int E = in_sizes[1] / 2;    // 800000
    const int* src = ei;
    const int* dst = ei + E;
    const int NB = (N + 1023) / 1024;  // 49

    // workspace carving (float units; pairs at base => 16B-aligned for float4 loads)
    float* ws = (float*)d_ws;
    float2* pairs = (float2*)ws;                  // [E]
    long off = 2L * E;
    int* posw   = (int*)(ws + off); off += E;
    int* deg    = (int*)(ws + off); off += N;
    int* rowptr = (int*)(ws + off); off += N + 1;
    int* bsum   = (int*)(ws + off); off += 64;
    float* dinv = ws + off;        off += N;
    off = (off + 3) & ~3L;
    f16* h1 = (f16*)(ws + off); off += (long)N * 64;   // N*128 fp16
    f16* z1 = (f16*)(ws + off); off += (long)N * 64;   // N*128 fp16
    f16* h2 = (f16*)(ws + off); off += (long)N * 32;   // N*64 fp16

    const int GB = (N + 63) / 64;     // 782 gemm blocks
    const int FB = (E + 255) / 256;   // 3125 fill/deg blocks

    // --- CSR build ---
    hipMemsetAsync(deg, 0, (size_t)N * sizeof(int), stream);
    deg_pos_kernel<<<FB, 256, 0, stream>>>(dst, deg, posw, E);
    scan1_kernel<<<NB, 1024, 0, stream>>>(deg, rowptr, bsum, dinv, N);
    scan23_kernel<<<NB, 1024, 0, stream>>>(rowptr, bsum, N, NB);

    // --- fused: gemm128 (x@W1 -> h1, W converted inline) + CSR fill ---
    fill_gemm_kernel<<<GB + FB, 256, 0, stream>>>(src, dst, posw, dinv, rowptr, pairs, E,
                                                  x, W1, h1, N, GB);

    // --- layer-1 gather, XCD-sharded by column group ---
    {
        const int tiles = (N + 31) / 32;           // 32 nodes per block
        gather128_shard_kernel<<<tiles * 8, 256, 0, stream>>>(
            (const __half2*)h1, rowptr, pairs, dinv, b1, (__half2*)z1, N);
    }

    // --- layer 2: h2 = f16(z1@W2); out = agg + self + b2 (fp32) ---
    gemm_kernel<64, false><<<(N + 63) / 64, 256, 0, stream>>>(z1, W2, h2, N);
    gather64_kernel<<<(N + 3) / 4, 256, 0, stream>>>(
        (const __half*)h2, rowptr, pairs, dinv, b2, out, N);
}